// Round 4
// baseline (157.666 us; speedup 1.0000x reference)
//
#include <hip/hip_runtime.h>
#include <hip/hip_bf16.h>
#include <math.h>

// Problem constants (B,C,H,W)=(4,128,64,64), NUM_HEADS=4
#define BB 4
#define CC 128
#define NH 4
#define DH 32
#define NN 4096
#define OC3 (3*CC)

typedef __attribute__((ext_vector_type(8))) short short8;   // 8 bf16 MFMA A/B frag
typedef __attribute__((ext_vector_type(4))) short short4v;
typedef __attribute__((ext_vector_type(4))) float float4v;  // MFMA C/D frag

__device__ inline short f2bf(float f) {     // RNE bf16 (scalar path)
    unsigned u = __builtin_bit_cast(unsigned, f);
    u += 0x7FFF + ((u >> 16) & 1);
    return (short)(u >> 16);
}
__device__ inline unsigned pk2bf(float a, float b) {  // low=bf16(a), high=bf16(b)
    __hip_bfloat162 h = __float22bfloat162_rn(make_float2(a, b));
    unsigned u; __builtin_memcpy(&u, &h, 4);
    return u;
}

// ---------------------------------------------------------------------------
// Kernel 0: one-time weight convert f32 -> bf16 (qkv_w 384x128 | proj_w 128x128).
// ---------------------------------------------------------------------------
__global__ __launch_bounds__(256) void wcvt_kernel(
        const float* __restrict__ qw, const float* __restrict__ pw,
        short* __restrict__ wb) {
    int i = (blockIdx.x * 256 + threadIdx.x) * 8;   // 32 blocks * 256 thr * 8 = 65536
    const float* src = (i < OC3 * CC) ? (qw + i) : (pw + (i - OC3 * CC));
    float4 f0 = *(const float4*)(src);
    float4 f1 = *(const float4*)(src + 4);
    union { short8 v; unsigned u[4]; } z;
    z.u[0] = pk2bf(f0.x, f0.y); z.u[1] = pk2bf(f0.z, f0.w);
    z.u[2] = pk2bf(f1.x, f1.y); z.u[3] = pk2bf(f1.z, f1.w);
    *(short8*)(wb + i) = z.v;
}

// ---------------------------------------------------------------------------
// Kernel 1: fused LayerNorm + QKV MFMA conv (R0 geometry: 64-n tiles, 256
// blocks — R3's tile-halving was neutral; reverted). bf16 weight loads.
// ---------------------------------------------------------------------------
#define HS 136
__global__ __launch_bounds__(512, 4) void lnqkv_kernel(
        const float* __restrict__ x, const float* __restrict__ nw,
        const float* __restrict__ nb, const short* __restrict__ qwb,
        const float* __restrict__ qbias,
        short* __restrict__ qT, short* __restrict__ kT, short* __restrict__ vv) {
    __shared__ short hT[64 * HS];
    __shared__ float red[16][64];
    __shared__ float mrs[2][64];
    int t = threadIdx.x;
    int n0g = blockIdx.x * 64;
    int b = n0g >> 12, n0 = n0g & (NN - 1);
    int nl = t & 63, cq = t >> 6;          // cq 0..7, owns 16 channels

    const float* xp = x + ((size_t)b * CC + cq * 16) * NN + n0 + nl;
    float xv[16];
    float s = 0.f, ss = 0.f;
    #pragma unroll
    for (int j = 0; j < 16; ++j) {
        xv[j] = xp[(size_t)j * NN];
        s += xv[j]; ss += xv[j] * xv[j];
    }
    red[cq][nl] = s; red[cq + 8][nl] = ss;
    __syncthreads();
    if (t < 64) {
        float s8 = 0.f, q8 = 0.f;
        #pragma unroll
        for (int j = 0; j < 8; ++j) { s8 += red[j][t]; q8 += red[j + 8][t]; }
        float mean = s8 * (1.0f / CC);
        float var  = q8 * (1.0f / CC) - mean * mean;
        mrs[0][t] = mean;
        mrs[1][t] = rsqrtf(var + 1e-6f);
    }
    __syncthreads();
    {
        float mean = mrs[0][nl], rsv = mrs[1][nl];
        #pragma unroll
        for (int j = 0; j < 16; j += 8) {
            union { short8 v; unsigned u[4]; } z;
            #pragma unroll
            for (int k = 0; k < 4; ++k) {
                int c = cq * 16 + j + 2 * k;
                float h0 = (xv[j + 2 * k]     - mean) * rsv * nw[c]     + nb[c];
                float h1 = (xv[j + 2 * k + 1] - mean) * rsv * nw[c + 1] + nb[c + 1];
                z.u[k] = pk2bf(h0, h1);
            }
            *(short8*)&hT[nl * HS + cq * 16 + j] = z.v;
        }
    }
    __syncthreads();

    int w = t >> 6, lane = t & 63;
    int lg = lane >> 4, ln = lane & 15;
    #pragma unroll
    for (int it = 0; it < 3; ++it) {
        int ow = (w + it * 8) * 16;
        const short* wp = qwb + (size_t)(ow + ln) * CC;
        float4v a0 = {0,0,0,0}, a1 = {0,0,0,0}, a2 = {0,0,0,0}, a3 = {0,0,0,0};
        #pragma unroll
        for (int cs = 0; cs < 4; ++cs) {
            short8 af = *(const short8*)(wp + cs * 32 + lg * 8);
            const short* hp = &hT[cs * 32 + lg * 8];
            a0 = __builtin_amdgcn_mfma_f32_16x16x32_bf16(af, *(const short8*)&hp[(0  + ln) * HS], a0, 0, 0, 0);
            a1 = __builtin_amdgcn_mfma_f32_16x16x32_bf16(af, *(const short8*)&hp[(16 + ln) * HS], a1, 0, 0, 0);
            a2 = __builtin_amdgcn_mfma_f32_16x16x32_bf16(af, *(const short8*)&hp[(32 + ln) * HS], a2, 0, 0, 0);
            a3 = __builtin_amdgcn_mfma_f32_16x16x32_bf16(af, *(const short8*)&hp[(48 + ln) * HS], a3, 0, 0, 0);
        }
        int r0 = ow + lg * 4;
        float b0 = qbias[r0], b1 = qbias[r0 + 1], b2 = qbias[r0 + 2], b3 = qbias[r0 + 3];
        int cb = ow & 31;
        float4v* accs[4] = {&a0, &a1, &a2, &a3};
        if (it == 0) {            // Q: scaled by scale*log2e
            const float qs = 0.1767766952966369f * 1.4426950408889634f;
            int hh = ow >> 5;
            size_t rowbase = (size_t)(b * NH + hh) * NN + n0;
            #pragma unroll
            for (int nsub = 0; nsub < 4; ++nsub) {
                float4v av = *accs[nsub];
                union { short4v v; unsigned u[2]; } z;
                z.u[0] = pk2bf((av.x + b0) * qs, (av.y + b1) * qs);
                z.u[1] = pk2bf((av.z + b2) * qs, (av.w + b3) * qs);
                *(short4v*)&qT[(rowbase + nsub * 16 + ln) * DH + cb + lg * 4] = z.v;
            }
        } else if (it == 1) {     // K
            int hh = (ow - CC) >> 5;
            size_t rowbase = (size_t)(b * NH + hh) * NN + n0;
            #pragma unroll
            for (int nsub = 0; nsub < 4; ++nsub) {
                float4v av = *accs[nsub];
                union { short4v v; unsigned u[2]; } z;
                z.u[0] = pk2bf(av.x + b0, av.y + b1);
                z.u[1] = pk2bf(av.z + b2, av.w + b3);
                *(short4v*)&kT[(rowbase + nsub * 16 + ln) * DH + cb + lg * 4] = z.v;
            }
        } else {                  // V: [bh][c][m]
            int hh = (ow - 2 * CC) >> 5;
            size_t cbase = (size_t)((b * NH + hh) * DH + cb + lg * 4);
            #pragma unroll
            for (int nsub = 0; nsub < 4; ++nsub) {
                float4v av = *accs[nsub];
                size_t col = (size_t)n0 + nsub * 16 + ln;
                vv[(cbase + 0) * NN + col] = f2bf(av.x + b0);
                vv[(cbase + 1) * NN + col] = f2bf(av.y + b1);
                vv[(cbase + 2) * NN + col] = f2bf(av.z + b2);
                vv[(cbase + 3) * NN + col] = f2bf(av.w + b3);
            }
        }
    }
}

// ---------------------------------------------------------------------------
// Kernel 2: MFMA flash attention v11. All per-j pipe experiments (permlane,
// mfma-rowsum, reg-prefetch) regressed: perf tracks OCCUPANCY (R0 33%/67us vs
// R1-R3 20%/74-77us). v11 raises the static wave ceiling 16 -> 32 waves/CU:
//   * split=8: block = 64 queries x 8 key-split waves; grid 16*64 = 1024
//     blocks = 4/CU of work (was 2/CU).
//   * LDS cut 55296 -> 40960 B (= 160KB/4 exactly -> 4 blocks/CU resident):
//     flat 3-buffer merge replaced by a 3-round TREE merge in [4][4][64][10]
//     floats (stride-10 pad: <=4-way ds conflicts; [8]=partial l, [9]=pad).
//   * inner loop = exact proven v7 body (VGPR 64; no prefetch).
// ---------------------------------------------------------------------------
#define PS 72
union __align__(16) FlashSh {
    short pt[8 * 16 * PS];                 // 18432 B  (P-bufs, main loop)
    float m[4][4][64][10];                 // 40960 B  (tree-merge, epilogue)
};
__global__ __launch_bounds__(512, 2) void flash_kernel(
        const short* __restrict__ qT, const short* __restrict__ kT,
        const short* __restrict__ vv, short* __restrict__ aoT) {
    __shared__ FlashSh sh;
    int blk = blockIdx.x;
    int bh = blk >> 6;            // 16 bh
    int qb = blk & 63;            // 64 query-tiles of 64
    int b = bh >> 2, hh = bh & 3;
    int n0 = qb * 64;
    int t = threadIdx.x, w = t >> 6, lane = t & 63;
    int lg = lane >> 4, ln = lane & 15;
    int split = w;                // key split 0..7 (512 keys each)

    const short* kbase = kT + (size_t)bh * NN * DH + lg * 8;
    const short* vb0 = vv + ((size_t)bh * DH + ln) * NN + lg * 8;
    const short* vb1 = vb0 + (size_t)16 * NN;

    short8 qf[4];
    #pragma unroll
    for (int j = 0; j < 4; ++j)
        qf[j] = *(const short8*)&qT[((size_t)bh * NN + n0 + j * 16 + ln) * DH + lg * 8];

    float4v o0[4], o1[4];
    float ls[4];
    #pragma unroll
    for (int j = 0; j < 4; ++j) {
        o0[j] = (float4v){0,0,0,0}; o1[j] = (float4v){0,0,0,0}; ls[j] = 0.f;
    }
    short* ptw = &sh.pt[w * 16 * PS];

    int mbeg = split * (NN / 8), mend = mbeg + NN / 8;
    for (int m0 = mbeg; m0 < mend; m0 += 64) {
        // ---- global loads: K frags (1KB/instr coalesced), V frags ----
        const short* kp = kbase + (size_t)m0 * DH;
        short8 k0 = *(const short8*)(kp + (size_t)(ln +  0) * DH);
        short8 k1 = *(const short8*)(kp + (size_t)(ln + 16) * DH);
        short8 k2 = *(const short8*)(kp + (size_t)(ln + 32) * DH);
        short8 k3 = *(const short8*)(kp + (size_t)(ln + 48) * DH);
        short8 v0 = *(const short8*)(vb0 + m0);
        short8 v1 = *(const short8*)(vb0 + m0 + 32);
        short8 v2 = *(const short8*)(vb1 + m0);
        short8 v3 = *(const short8*)(vb1 + m0 + 32);

        // ---- per q-tile: QK -> softmax -> pack -> PV (one P-buf, reused;
        //      in-order same-wave DS queue keeps write_j/read_j correct) ----
        #pragma unroll
        for (int j = 0; j < 4; ++j) {
            float4v s0 = {0,0,0,0}, s1 = s0, s2 = s0, s3 = s0;
            s0 = __builtin_amdgcn_mfma_f32_16x16x32_bf16(k0, qf[j], s0, 0, 0, 0);
            s1 = __builtin_amdgcn_mfma_f32_16x16x32_bf16(k1, qf[j], s1, 0, 0, 0);
            s2 = __builtin_amdgcn_mfma_f32_16x16x32_bf16(k2, qf[j], s2, 0, 0, 0);
            s3 = __builtin_amdgcn_mfma_f32_16x16x32_bf16(k3, qf[j], s3, 0, 0, 0);
            float lacc = 0.f;
            float4v* sv[4] = {&s0, &s1, &s2, &s3};
            #pragma unroll
            for (int jj = 0; jj < 4; ++jj) {
                float4v sj = *sv[jj];
                float p0 = __builtin_amdgcn_exp2f(sj.x);
                float p1 = __builtin_amdgcn_exp2f(sj.y);
                float p2 = __builtin_amdgcn_exp2f(sj.z);
                float p3 = __builtin_amdgcn_exp2f(sj.w);
                lacc += (p0 + p1) + (p2 + p3);
                union { short4v v; unsigned u[2]; } z;
                z.u[0] = pk2bf(p0, p1); z.u[1] = pk2bf(p2, p3);
                *(short4v*)&ptw[ln * PS + jj * 16 + lg * 4] = z.v;
            }
            ls[j] += lacc;
            short8 pb0 = *(const short8*)&ptw[ln * PS + 0  + lg * 8];
            short8 pb1 = *(const short8*)&ptw[ln * PS + 32 + lg * 8];
            o0[j] = __builtin_amdgcn_mfma_f32_16x16x32_bf16(v0, pb0, o0[j], 0, 0, 0);
            o1[j] = __builtin_amdgcn_mfma_f32_16x16x32_bf16(v2, pb0, o1[j], 0, 0, 0);
            o0[j] = __builtin_amdgcn_mfma_f32_16x16x32_bf16(v1, pb1, o0[j], 0, 0, 0);
            o1[j] = __builtin_amdgcn_mfma_f32_16x16x32_bf16(v3, pb1, o1[j], 0, 0, 0);
        }
    }

    // ---- tree merge of the 8 key-splits (3 rounds, 4-slot buffer) ----
    __syncthreads();                      // everyone done with pt alias
    {
        // round 1: odd splits publish, even splits absorb partner (s+1)
        if (split & 1) {
            int slot = split >> 1;
            #pragma unroll
            for (int j = 0; j < 4; ++j) {
                float* mp = &sh.m[slot][j][lane][0];
                *(float2*)(mp + 0) = make_float2(o0[j].x, o0[j].y);
                *(float2*)(mp + 2) = make_float2(o0[j].z, o0[j].w);
                *(float2*)(mp + 4) = make_float2(o1[j].x, o1[j].y);
                *(float2*)(mp + 6) = make_float2(o1[j].z, o1[j].w);
                mp[8] = ls[j];
            }
        }
        __syncthreads();
        if (!(split & 1)) {
            int slot = split >> 1;
            #pragma unroll
            for (int j = 0; j < 4; ++j) {
                const float* mp = &sh.m[slot][j][lane][0];
                float2 a0 = *(const float2*)(mp + 0);
                float2 a1 = *(const float2*)(mp + 2);
                float2 a2 = *(const float2*)(mp + 4);
                float2 a3 = *(const float2*)(mp + 6);
                o0[j].x += a0.x; o0[j].y += a0.y; o0[j].z += a1.x; o0[j].w += a1.y;
                o1[j].x += a2.x; o1[j].y += a2.y; o1[j].z += a3.x; o1[j].w += a3.y;
                ls[j] += mp[8];
            }
        }
        __syncthreads();
        // round 2: splits 2,6 publish; splits 0,4 absorb
        if ((split & 3) == 2) {
            int slot = split >> 2;
            #pragma unroll
            for (int j = 0; j < 4; ++j) {
                float* mp = &sh.m[slot][j][lane][0];
                *(float2*)(mp + 0) = make_float2(o0[j].x, o0[j].y);
                *(float2*)(mp + 2) = make_float2(o0[j].z, o0[j].w);
                *(float2*)(mp + 4) = make_float2(o1[j].x, o1[j].y);
                *(float2*)(mp + 6) = make_float2(o1[j].z, o1[j].w);
                mp[8] = ls[j];
            }
        }
        __syncthreads();
        if ((split & 3) == 0) {
            int slot = split >> 2;
            #pragma unroll
            for (int j = 0; j < 4; ++j) {
                const float* mp = &sh.m[slot][j][lane][0];
                float2 a0 = *(const float2*)(mp + 0);
                float2 a1 = *(const float2*)(mp + 2);
                float2 a2 = *(const float2*)(mp + 4);
                float2 a3 = *(const float2*)(mp + 6);
                o0[j].x += a0.x; o0[j].y += a0.y; o0[j].z += a1.x; o0[j].w += a1.y;
                o1[j].x += a2.x; o1[j].y += a2.y; o1[j].z += a3.x; o1[j].w += a3.y;
                ls[j] += mp[8];
            }
        }
        __syncthreads();
        // round 3: split 4 publishes; split 0 absorbs + stores
        if (split == 4) {
            #pragma unroll
            for (int j = 0; j < 4; ++j) {
                float* mp = &sh.m[0][j][lane][0];
                *(float2*)(mp + 0) = make_float2(o0[j].x, o0[j].y);
                *(float2*)(mp + 2) = make_float2(o0[j].z, o0[j].w);
                *(float2*)(mp + 4) = make_float2(o1[j].x, o1[j].y);
                *(float2*)(mp + 6) = make_float2(o1[j].z, o1[j].w);
                mp[8] = ls[j];
            }
        }
        __syncthreads();
        if (split == 0) {
            #pragma unroll
            for (int j = 0; j < 4; ++j) {
                const float* mp = &sh.m[0][j][lane][0];
                float2 a0 = *(const float2*)(mp + 0);
                float2 a1 = *(const float2*)(mp + 2);
                float2 a2 = *(const float2*)(mp + 4);
                float2 a3 = *(const float2*)(mp + 6);
                o0[j].x += a0.x; o0[j].y += a0.y; o0[j].z += a1.x; o0[j].w += a1.y;
                o1[j].x += a2.x; o1[j].y += a2.y; o1[j].z += a3.x; o1[j].w += a3.y;
                ls[j] += mp[8];

                float lt = ls[j];
                lt += __shfl_xor(lt, 16, 64);
                lt += __shfl_xor(lt, 32, 64);
                float inv = 1.0f / lt;
                short* ap = aoT + ((size_t)b * NN + n0 + j * 16 + ln) * CC + hh * DH;
                union { short4v v; unsigned u[2]; } z;
                z.u[0] = pk2bf(o0[j].x * inv, o0[j].y * inv);
                z.u[1] = pk2bf(o0[j].z * inv, o0[j].w * inv);
                *(short4v*)&ap[lg * 4] = z.v;
                z.u[0] = pk2bf(o1[j].x * inv, o1[j].y * inv);
                z.u[1] = pk2bf(o1[j].z * inv, o1[j].w * inv);
                *(short4v*)&ap[16 + lg * 4] = z.v;
            }
        }
    }
}

// ---------------------------------------------------------------------------
// Kernel 3: proj MFMA conv + bias + residual (fp32 out), bf16 weight loads.
// R0 geometry (64-n tiles, grid (256,2)) — R3's halving was neutral; reverted.
// ---------------------------------------------------------------------------
__global__ __launch_bounds__(256) void proj_kernel(
        const short* __restrict__ aoT, const short* __restrict__ pwb,
        const float* __restrict__ pb, const float* __restrict__ x,
        float* __restrict__ out) {
    int t = threadIdx.x;
    int n0g = blockIdx.x * 64;
    int b = n0g >> 12, n0 = n0g & (NN - 1);
    int o0 = blockIdx.y * 64;
    int wo = t >> 6, lane = t & 63;
    int lg = lane >> 4, ln = lane & 15;
    int ow = o0 + wo * 16;
    const short* wp = pwb + (size_t)(ow + ln) * CC;
    const short* ap = aoT + (size_t)n0g * CC + lg * 8;
    float4v a0 = {0,0,0,0}, a1 = {0,0,0,0}, a2 = {0,0,0,0}, a3 = {0,0,0,0};
    #pragma unroll
    for (int cs = 0; cs < 4; ++cs) {
        short8 af = *(const short8*)(wp + cs * 32 + lg * 8);
        const short* hp = ap + cs * 32;
        a0 = __builtin_amdgcn_mfma_f32_16x16x32_bf16(af, *(const short8*)&hp[(size_t)(0  + ln) * CC], a0, 0, 0, 0);
        a1 = __builtin_amdgcn_mfma_f32_16x16x32_bf16(af, *(const short8*)&hp[(size_t)(16 + ln) * CC], a1, 0, 0, 0);
        a2 = __builtin_amdgcn_mfma_f32_16x16x32_bf16(af, *(const short8*)&hp[(size_t)(32 + ln) * CC], a2, 0, 0, 0);
        a3 = __builtin_amdgcn_mfma_f32_16x16x32_bf16(af, *(const short8*)&hp[(size_t)(48 + ln) * CC], a3, 0, 0, 0);
    }
    int r0 = ow + lg * 4;
    float b0 = pb[r0], b1 = pb[r0 + 1], b2 = pb[r0 + 2], b3 = pb[r0 + 3];
    const float* xbase = x   + ((size_t)b * CC + r0) * NN + n0 + ln;
    float*       obase = out + ((size_t)b * CC + r0) * NN + n0 + ln;
    float4v* accs[4] = {&a0, &a1, &a2, &a3};
    #pragma unroll
    for (int nsub = 0; nsub < 4; ++nsub) {
        float4v av = *accs[nsub];
        const float* xp = xbase + nsub * 16;
        float* op = obase + nsub * 16;
        op[(size_t)0 * NN] = av.x + b0 + xp[(size_t)0 * NN];
        op[(size_t)1 * NN] = av.y + b1 + xp[(size_t)1 * NN];
        op[(size_t)2 * NN] = av.z + b2 + xp[(size_t)2 * NN];
        op[(size_t)3 * NN] = av.w + b3 + xp[(size_t)3 * NN];
    }
}

// ---------------------------------------------------------------------------
extern "C" void kernel_launch(void* const* d_in, const int* in_sizes, int n_in,
                              void* d_out, int out_size, void* d_ws, size_t ws_size,
                              hipStream_t stream) {
    const float* x    = (const float*)d_in[0];
    const float* nw   = (const float*)d_in[1];
    const float* nb   = (const float*)d_in[2];
    const float* qkvw = (const float*)d_in[3];
    const float* qkvb = (const float*)d_in[4];
    const float* pw   = (const float*)d_in[5];
    const float* pb   = (const float*)d_in[6];
    float* out = (float*)d_out;

    // ws (shorts): qT | kT | v | aoT (4 MB each) | wb (128 KB bf16 weights)
    short* qT  = (short*)d_ws;
    short* kT  = qT + (size_t)BB * NH * NN * DH;
    short* vv  = kT + (size_t)BB * NH * NN * DH;
    short* aoT = vv + (size_t)BB * NH * DH * NN;
    short* wb  = aoT + (size_t)BB * NH * DH * NN;
    short* qwb = wb;
    short* pwb = wb + (size_t)OC3 * CC;

    wcvt_kernel<<<dim3(32), 256, 0, stream>>>(qkvw, pw, wb);
    lnqkv_kernel<<<dim3(256), 512, 0, stream>>>(x, nw, nb, qwb, qkvb, qT, kT, vv);
    flash_kernel<<<dim3(1024), 512, 0, stream>>>(qT, kT, vv, aoT);
    proj_kernel<<<dim3(256, 2), 256, 0, stream>>>(aoT, pwb, pb, x, out);
}

// Round 5
// 147.964 us; speedup vs baseline: 1.0656x; 1.0656x over previous
//
#include <hip/hip_runtime.h>
#include <hip/hip_bf16.h>
#include <math.h>

// Problem constants (B,C,H,W)=(4,128,64,64), NUM_HEADS=4
#define BB 4
#define CC 128
#define NH 4
#define DH 32
#define NN 4096
#define OC3 (3*CC)

typedef __attribute__((ext_vector_type(8))) short short8;   // 8 bf16 MFMA A/B frag
typedef __attribute__((ext_vector_type(4))) short short4v;
typedef __attribute__((ext_vector_type(4))) float float4v;  // MFMA C/D frag

__device__ inline short f2bf(float f) {     // RNE bf16 (scalar path)
    unsigned u = __builtin_bit_cast(unsigned, f);
    u += 0x7FFF + ((u >> 16) & 1);
    return (short)(u >> 16);
}
__device__ inline unsigned pk2bf(float a, float b) {  // low=bf16(a), high=bf16(b)
    __hip_bfloat162 h = __float22bfloat162_rn(make_float2(a, b));
    unsigned u; __builtin_memcpy(&u, &h, 4);
    return u;
}

// ---------------------------------------------------------------------------
// Kernel 0: one-time weight convert f32 -> bf16 (qkv_w 384x128 | proj_w 128x128).
// ---------------------------------------------------------------------------
__global__ __launch_bounds__(256) void wcvt_kernel(
        const float* __restrict__ qw, const float* __restrict__ pw,
        short* __restrict__ wb) {
    int i = (blockIdx.x * 256 + threadIdx.x) * 8;   // 32 blocks * 256 thr * 8 = 65536
    const float* src = (i < OC3 * CC) ? (qw + i) : (pw + (i - OC3 * CC));
    float4 f0 = *(const float4*)(src);
    float4 f1 = *(const float4*)(src + 4);
    union { short8 v; unsigned u[4]; } z;
    z.u[0] = pk2bf(f0.x, f0.y); z.u[1] = pk2bf(f0.z, f0.w);
    z.u[2] = pk2bf(f1.x, f1.y); z.u[3] = pk2bf(f1.z, f1.w);
    *(short8*)(wb + i) = z.v;
}

// ---------------------------------------------------------------------------
// Kernel 1: fused LayerNorm + QKV MFMA conv. v12: front-end vectorized —
// thread = (token-quad, 4-ch group): 4x float4 x-loads (16B/lane, was 16x 4B),
// LN partials via [2][32][68] LDS, pack to the SAME hT layout. MFMA/store
// phases byte-identical to the proven R0 structure. bf16 weight loads.
// ---------------------------------------------------------------------------
#define HS 136
__global__ __launch_bounds__(512, 4) void lnqkv_kernel(
        const float* __restrict__ x, const float* __restrict__ nw,
        const float* __restrict__ nb, const short* __restrict__ qwb,
        const float* __restrict__ qbias,
        short* __restrict__ qT, short* __restrict__ kT, short* __restrict__ vv) {
    __shared__ short hT[64 * HS];
    __shared__ float red[2][32][68];
    __shared__ float mrs[2][64];
    int t = threadIdx.x;
    int n0g = blockIdx.x * 64;
    int b = n0g >> 12, n0 = n0g & (NN - 1);
    int nq = t & 15;            // token quad: tokens nq*4 .. nq*4+3
    int cg = t >> 4;            // 0..31: channels cg*4 .. cg*4+3

    const float* xb = x + ((size_t)b * CC + cg * 4) * NN + n0 + nq * 4;
    float xe[4][4];             // [c][k] all constant-indexed
    {
        float s0 = 0.f, s1 = 0.f, s2 = 0.f, s3 = 0.f;
        float q0 = 0.f, q1 = 0.f, q2 = 0.f, q3 = 0.f;
        #pragma unroll
        for (int c = 0; c < 4; ++c) {
            float4 v = *(const float4*)(xb + (size_t)c * NN);
            xe[c][0] = v.x; xe[c][1] = v.y; xe[c][2] = v.z; xe[c][3] = v.w;
            s0 += v.x; q0 += v.x * v.x;
            s1 += v.y; q1 += v.y * v.y;
            s2 += v.z; q2 += v.z * v.z;
            s3 += v.w; q3 += v.w * v.w;
        }
        *(float4*)&red[0][cg][nq * 4] = make_float4(s0, s1, s2, s3);
        *(float4*)&red[1][cg][nq * 4] = make_float4(q0, q1, q2, q3);
    }
    __syncthreads();
    if (t < 64) {
        float s8 = 0.f, q8 = 0.f;
        #pragma unroll
        for (int j = 0; j < 32; ++j) { s8 += red[0][j][t]; q8 += red[1][j][t]; }
        float mean = s8 * (1.0f / CC);
        float var  = q8 * (1.0f / CC) - mean * mean;
        mrs[0][t] = mean;
        mrs[1][t] = rsqrtf(var + 1e-6f);
    }
    __syncthreads();
    {
        int c0 = cg * 4;
        float w0 = nw[c0], w1 = nw[c0 + 1], w2 = nw[c0 + 2], w3 = nw[c0 + 3];
        float e0 = nb[c0], e1 = nb[c0 + 1], e2 = nb[c0 + 2], e3 = nb[c0 + 3];
        #pragma unroll
        for (int k = 0; k < 4; ++k) {
            int token = nq * 4 + k;
            float m = mrs[0][token], r = mrs[1][token];
            float h0 = (xe[0][k] - m) * r * w0 + e0;
            float h1 = (xe[1][k] - m) * r * w1 + e1;
            float h2 = (xe[2][k] - m) * r * w2 + e2;
            float h3 = (xe[3][k] - m) * r * w3 + e3;
            union { short4v v; unsigned u[2]; } z;
            z.u[0] = pk2bf(h0, h1); z.u[1] = pk2bf(h2, h3);
            *(short4v*)&hT[token * HS + c0] = z.v;
        }
    }
    __syncthreads();

    int w = t >> 6, lane = t & 63;
    int lg = lane >> 4, ln = lane & 15;
    #pragma unroll
    for (int it = 0; it < 3; ++it) {
        int ow = (w + it * 8) * 16;
        const short* wp = qwb + (size_t)(ow + ln) * CC;
        float4v a0 = {0,0,0,0}, a1 = {0,0,0,0}, a2 = {0,0,0,0}, a3 = {0,0,0,0};
        #pragma unroll
        for (int cs = 0; cs < 4; ++cs) {
            short8 af = *(const short8*)(wp + cs * 32 + lg * 8);
            const short* hp = &hT[cs * 32 + lg * 8];
            a0 = __builtin_amdgcn_mfma_f32_16x16x32_bf16(af, *(const short8*)&hp[(0  + ln) * HS], a0, 0, 0, 0);
            a1 = __builtin_amdgcn_mfma_f32_16x16x32_bf16(af, *(const short8*)&hp[(16 + ln) * HS], a1, 0, 0, 0);
            a2 = __builtin_amdgcn_mfma_f32_16x16x32_bf16(af, *(const short8*)&hp[(32 + ln) * HS], a2, 0, 0, 0);
            a3 = __builtin_amdgcn_mfma_f32_16x16x32_bf16(af, *(const short8*)&hp[(48 + ln) * HS], a3, 0, 0, 0);
        }
        int r0 = ow + lg * 4;
        float b0 = qbias[r0], b1 = qbias[r0 + 1], b2 = qbias[r0 + 2], b3 = qbias[r0 + 3];
        int cb = ow & 31;
        float4v* accs[4] = {&a0, &a1, &a2, &a3};
        if (it == 0) {            // Q: scaled by scale*log2e
            const float qs = 0.1767766952966369f * 1.4426950408889634f;
            int hh = ow >> 5;
            size_t rowbase = (size_t)(b * NH + hh) * NN + n0;
            #pragma unroll
            for (int nsub = 0; nsub < 4; ++nsub) {
                float4v av = *accs[nsub];
                union { short4v v; unsigned u[2]; } z;
                z.u[0] = pk2bf((av.x + b0) * qs, (av.y + b1) * qs);
                z.u[1] = pk2bf((av.z + b2) * qs, (av.w + b3) * qs);
                *(short4v*)&qT[(rowbase + nsub * 16 + ln) * DH + cb + lg * 4] = z.v;
            }
        } else if (it == 1) {     // K
            int hh = (ow - CC) >> 5;
            size_t rowbase = (size_t)(b * NH + hh) * NN + n0;
            #pragma unroll
            for (int nsub = 0; nsub < 4; ++nsub) {
                float4v av = *accs[nsub];
                union { short4v v; unsigned u[2]; } z;
                z.u[0] = pk2bf(av.x + b0, av.y + b1);
                z.u[1] = pk2bf(av.z + b2, av.w + b3);
                *(short4v*)&kT[(rowbase + nsub * 16 + ln) * DH + cb + lg * 4] = z.v;
            }
        } else {                  // V: [bh][c][m]
            int hh = (ow - 2 * CC) >> 5;
            size_t cbase = (size_t)((b * NH + hh) * DH + cb + lg * 4);
            #pragma unroll
            for (int nsub = 0; nsub < 4; ++nsub) {
                float4v av = *accs[nsub];
                size_t col = (size_t)n0 + nsub * 16 + ln;
                vv[(cbase + 0) * NN + col] = f2bf(av.x + b0);
                vv[(cbase + 1) * NN + col] = f2bf(av.y + b1);
                vv[(cbase + 2) * NN + col] = f2bf(av.z + b2);
                vv[(cbase + 3) * NN + col] = f2bf(av.w + b3);
            }
        }
    }
}

// ---------------------------------------------------------------------------
// Kernel 2: MFMA flash attention v7 — EXACT R0 restore (67.2 us measured).
// Four structural experiments (permlane transpose, mfma-rowsum, reg-prefetch,
// split-8 tree merge) all regressed: any live set >64 VGPR drops to 4 waves/
// SIMD and costs ~8-13 us. Do not touch the inner loop.
// ---------------------------------------------------------------------------
#define PS 72
union __align__(16) FlashSh {
    short pt[8 * 16 * PS];                       // 1 P-buf per wave (18432 B)
    struct { float mo[3][8][64][8]; float ml[3][8][64]; } m;  // 55296 B
};
__global__ __launch_bounds__(512, 2) void flash_kernel(
        const short* __restrict__ qT, const short* __restrict__ kT,
        const short* __restrict__ vv, short* __restrict__ aoT) {
    __shared__ FlashSh sh;
    int blk = blockIdx.x;
    int bh = blk >> 5;
    int qb = blk & 31;
    int b = bh >> 2, hh = bh & 3;
    int n0 = qb * 128;
    int t = threadIdx.x, w = t >> 6, lane = t & 63;
    int lg = lane >> 4, ln = lane & 15;
    int qg = w & 1;               // which 64-query group of the block's 128
    int split = w >> 1;           // key split 0..3

    const short* kbase = kT + (size_t)bh * NN * DH + lg * 8;
    const short* vb0 = vv + ((size_t)bh * DH + ln) * NN + lg * 8;
    const short* vb1 = vb0 + (size_t)16 * NN;

    short8 qf[4];
    #pragma unroll
    for (int j = 0; j < 4; ++j)
        qf[j] = *(const short8*)&qT[((size_t)bh * NN + n0 + (qg * 4 + j) * 16 + ln) * DH + lg * 8];

    float4v o0[4], o1[4];
    float ls[4];
    #pragma unroll
    for (int j = 0; j < 4; ++j) {
        o0[j] = (float4v){0,0,0,0}; o1[j] = (float4v){0,0,0,0}; ls[j] = 0.f;
    }
    short* ptw = &sh.pt[w * 16 * PS];

    int mbeg = split * (NN / 4), mend = mbeg + NN / 4;
    for (int m0 = mbeg; m0 < mend; m0 += 64) {
        // ---- shared loads: K frags (1KB/instr coalesced), V frags ----
        const short* kp = kbase + (size_t)m0 * DH;
        short8 k0 = *(const short8*)(kp + (size_t)(ln +  0) * DH);
        short8 k1 = *(const short8*)(kp + (size_t)(ln + 16) * DH);
        short8 k2 = *(const short8*)(kp + (size_t)(ln + 32) * DH);
        short8 k3 = *(const short8*)(kp + (size_t)(ln + 48) * DH);
        short8 v0 = *(const short8*)(vb0 + m0);
        short8 v1 = *(const short8*)(vb0 + m0 + 32);
        short8 v2 = *(const short8*)(vb1 + m0);
        short8 v3 = *(const short8*)(vb1 + m0 + 32);

        // ---- per q-tile: QK -> softmax -> pack -> PV (one P-buf, reused;
        //      in-order same-wave DS queue keeps write_j/read_j correct) ----
        #pragma unroll
        for (int j = 0; j < 4; ++j) {
            float4v s0 = {0,0,0,0}, s1 = s0, s2 = s0, s3 = s0;
            s0 = __builtin_amdgcn_mfma_f32_16x16x32_bf16(k0, qf[j], s0, 0, 0, 0);
            s1 = __builtin_amdgcn_mfma_f32_16x16x32_bf16(k1, qf[j], s1, 0, 0, 0);
            s2 = __builtin_amdgcn_mfma_f32_16x16x32_bf16(k2, qf[j], s2, 0, 0, 0);
            s3 = __builtin_amdgcn_mfma_f32_16x16x32_bf16(k3, qf[j], s3, 0, 0, 0);
            float lacc = 0.f;
            float4v* sv[4] = {&s0, &s1, &s2, &s3};
            #pragma unroll
            for (int jj = 0; jj < 4; ++jj) {
                float4v sj = *sv[jj];
                float p0 = __builtin_amdgcn_exp2f(sj.x);
                float p1 = __builtin_amdgcn_exp2f(sj.y);
                float p2 = __builtin_amdgcn_exp2f(sj.z);
                float p3 = __builtin_amdgcn_exp2f(sj.w);
                lacc += (p0 + p1) + (p2 + p3);
                union { short4v v; unsigned u[2]; } z;
                z.u[0] = pk2bf(p0, p1); z.u[1] = pk2bf(p2, p3);
                *(short4v*)&ptw[ln * PS + jj * 16 + lg * 4] = z.v;
            }
            ls[j] += lacc;
            short8 pb0 = *(const short8*)&ptw[ln * PS + 0  + lg * 8];
            short8 pb1 = *(const short8*)&ptw[ln * PS + 32 + lg * 8];
            o0[j] = __builtin_amdgcn_mfma_f32_16x16x32_bf16(v0, pb0, o0[j], 0, 0, 0);
            o1[j] = __builtin_amdgcn_mfma_f32_16x16x32_bf16(v2, pb0, o1[j], 0, 0, 0);
            o0[j] = __builtin_amdgcn_mfma_f32_16x16x32_bf16(v1, pb1, o0[j], 0, 0, 0);
            o1[j] = __builtin_amdgcn_mfma_f32_16x16x32_bf16(v3, pb1, o1[j], 0, 0, 0);
        }
    }

    // ---- all waves done with pt before aliasing it as merge buffers ----
    __syncthreads();
    if (split > 0) {
        int si = split - 1;
        #pragma unroll
        for (int j = 0; j < 4; ++j) {
            int tid = qg * 4 + j;
            float* mp = &sh.m.mo[si][tid][lane][0];
            *(float4*)(mp + 0) = make_float4(o0[j].x, o0[j].y, o0[j].z, o0[j].w);
            *(float4*)(mp + 4) = make_float4(o1[j].x, o1[j].y, o1[j].z, o1[j].w);
            sh.m.ml[si][tid][lane] = ls[j];
        }
    }
    __syncthreads();
    if (split == 0) {
        #pragma unroll
        for (int j = 0; j < 4; ++j) {
            int tid = qg * 4 + j;
            #pragma unroll
            for (int si = 0; si < 3; ++si) {
                const float* mp = &sh.m.mo[si][tid][lane][0];
                float4 a0 = *(const float4*)(mp + 0);
                float4 a1 = *(const float4*)(mp + 4);
                o0[j].x += a0.x; o0[j].y += a0.y; o0[j].z += a0.z; o0[j].w += a0.w;
                o1[j].x += a1.x; o1[j].y += a1.y; o1[j].z += a1.z; o1[j].w += a1.w;
                ls[j] += sh.m.ml[si][tid][lane];
            }
            float lt = ls[j];
            lt += __shfl_xor(lt, 16, 64);
            lt += __shfl_xor(lt, 32, 64);
            float inv = 1.0f / lt;
            short* ap = aoT + ((size_t)b * NN + n0 + tid * 16 + ln) * CC + hh * DH;
            union { short4v v; unsigned u[2]; } z;
            z.u[0] = pk2bf(o0[j].x * inv, o0[j].y * inv);
            z.u[1] = pk2bf(o0[j].z * inv, o0[j].w * inv);
            *(short4v*)&ap[lg * 4] = z.v;
            z.u[0] = pk2bf(o1[j].x * inv, o1[j].y * inv);
            z.u[1] = pk2bf(o1[j].z * inv, o1[j].w * inv);
            *(short4v*)&ap[16 + lg * 4] = z.v;
        }
    }
}

// ---------------------------------------------------------------------------
// Kernel 3: proj MFMA conv + bias + residual (fp32 out). v12: LDS-transpose
// epilogue — accs staged through [64][68] f32, then each lane owns 1 channel x
// 4 consecutive tokens so x-read / out-write are float4 with 256B-contiguous
// rows (was 64B segments). MFMA part unchanged; bias applied post-transpose.
// ---------------------------------------------------------------------------
__global__ __launch_bounds__(256) void proj_kernel(
        const short* __restrict__ aoT, const short* __restrict__ pwb,
        const float* __restrict__ pb, const float* __restrict__ x,
        float* __restrict__ out) {
    __shared__ float ot[64][68];
    int t = threadIdx.x;
    int n0g = blockIdx.x * 64;
    int b = n0g >> 12, n0 = n0g & (NN - 1);
    int o0 = blockIdx.y * 64;
    int wo = t >> 6, lane = t & 63;
    int lg = lane >> 4, ln = lane & 15;
    int ow = o0 + wo * 16;
    const short* wp = pwb + (size_t)(ow + ln) * CC;
    const short* ap = aoT + (size_t)n0g * CC + lg * 8;
    float4v a0 = {0,0,0,0}, a1 = {0,0,0,0}, a2 = {0,0,0,0}, a3 = {0,0,0,0};
    #pragma unroll
    for (int cs = 0; cs < 4; ++cs) {
        short8 af = *(const short8*)(wp + cs * 32 + lg * 8);
        const short* hp = ap + cs * 32;
        a0 = __builtin_amdgcn_mfma_f32_16x16x32_bf16(af, *(const short8*)&hp[(size_t)(0  + ln) * CC], a0, 0, 0, 0);
        a1 = __builtin_amdgcn_mfma_f32_16x16x32_bf16(af, *(const short8*)&hp[(size_t)(16 + ln) * CC], a1, 0, 0, 0);
        a2 = __builtin_amdgcn_mfma_f32_16x16x32_bf16(af, *(const short8*)&hp[(size_t)(32 + ln) * CC], a2, 0, 0, 0);
        a3 = __builtin_amdgcn_mfma_f32_16x16x32_bf16(af, *(const short8*)&hp[(size_t)(48 + ln) * CC], a3, 0, 0, 0);
    }
    // stage accs: ot[local ch][token]
    {
        int chb = wo * 16 + lg * 4;
        float4v* accs[4] = {&a0, &a1, &a2, &a3};
        #pragma unroll
        for (int nsub = 0; nsub < 4; ++nsub) {
            float4v av = *accs[nsub];
            int tok = nsub * 16 + ln;
            ot[chb + 0][tok] = av.x;
            ot[chb + 1][tok] = av.y;
            ot[chb + 2][tok] = av.z;
            ot[chb + 3][tok] = av.w;
        }
    }
    __syncthreads();
    // transposed IO: lane = (token-quad tq, ch-group cg); 4 channels per thread
    {
        int tq = t & 15, cg = t >> 4;     // cg 0..15
        #pragma unroll
        for (int i = 0; i < 4; ++i) {
            int chl = cg + i * 16;        // 0..63
            int chg = o0 + chl;
            float4 o4 = *(const float4*)&ot[chl][tq * 4];
            float bias = pb[chg];
            const float* xp = x + ((size_t)b * CC + chg) * NN + n0 + tq * 4;
            float*       op = out + ((size_t)b * CC + chg) * NN + n0 + tq * 4;
            float4 xr = *(const float4*)xp;
            *(float4*)op = make_float4(o4.x + bias + xr.x, o4.y + bias + xr.y,
                                       o4.z + bias + xr.z, o4.w + bias + xr.w);
        }
    }
}

// ---------------------------------------------------------------------------
extern "C" void kernel_launch(void* const* d_in, const int* in_sizes, int n_in,
                              void* d_out, int out_size, void* d_ws, size_t ws_size,
                              hipStream_t stream) {
    const float* x    = (const float*)d_in[0];
    const float* nw   = (const float*)d_in[1];
    const float* nb   = (const float*)d_in[2];
    const float* qkvw = (const float*)d_in[3];
    const float* qkvb = (const float*)d_in[4];
    const float* pw   = (const float*)d_in[5];
    const float* pb   = (const float*)d_in[6];
    float* out = (float*)d_out;

    // ws (shorts): qT | kT | v | aoT (4 MB each) | wb (128 KB bf16 weights)
    short* qT  = (short*)d_ws;
    short* kT  = qT + (size_t)BB * NH * NN * DH;
    short* vv  = kT + (size_t)BB * NH * NN * DH;
    short* aoT = vv + (size_t)BB * NH * DH * NN;
    short* wb  = aoT + (size_t)BB * NH * DH * NN;
    short* qwb = wb;
    short* pwb = wb + (size_t)OC3 * CC;

    wcvt_kernel<<<dim3(32), 256, 0, stream>>>(qkvw, pw, wb);
    lnqkv_kernel<<<dim3(256), 512, 0, stream>>>(x, nw, nb, qwb, qkvb, qT, kT, vv);
    flash_kernel<<<dim3(512), 512, 0, stream>>>(qT, kT, vv, aoT);
    proj_kernel<<<dim3(256, 2), 256, 0, stream>>>(aoT, pwb, pb, x, out);
}